// Round 2
// baseline (3312.333 us; speedup 1.0000x reference)
//
#include <hip/hip_runtime.h>
#include <stdint.h>

// ---------------------------------------------------------------------------
// TransformerDecoder on MI355X.
// Key facts exploited:
//  * reference MHA reduces to diag(softmax(QK^T)) * V  (elementwise scale)
//  * FFN (run twice per layer) is 94% of FLOPs -> bf16 MFMA GEMM everywhere
//  * all weights transposed+converted to bf16 (B^T layout) once per call
// ---------------------------------------------------------------------------

typedef unsigned short u16;   // raw bf16 storage
typedef unsigned int   u32;
typedef __attribute__((ext_vector_type(8))) short s16x8;   // 8 bf16 (4 VGPRs)
typedef __attribute__((ext_vector_type(4))) float f32x4;

#define AS1 __attribute__((address_space(1)))
#define AS3 __attribute__((address_space(3)))

__device__ __forceinline__ float bf2f(u16 h) { return __uint_as_float(((u32)h) << 16); }
__device__ __forceinline__ u16 f2bf(float f) {
  u32 u = __float_as_uint(f);
  u32 r = (u + 0x7fffu + ((u >> 16) & 1u)) >> 16;   // round-to-nearest-even
  return (u16)r;
}
__device__ __forceinline__ void gl_lds16(const u16* g, u16* l) {
  __builtin_amdgcn_global_load_lds((const AS1 void*)g, (AS3 void*)l, 16, 0, 0);
}

// ---------------------------------------------------------------------------
// bf16 GEMM:  C[M,N] = A[M,K] @ Bt[N,K]^T   (m97 structure: 128x128 tile, BK=32)
// grid = (M/128, Npad/128, SPLITS); blockIdx.z offsets K by z*K and C by z*sstride
// ---------------------------------------------------------------------------
template<bool BIAS, bool RELU, bool OBF>
__global__ __launch_bounds__(256, 2)
void gemm_bt(const u16* __restrict__ A, int lda,
             const u16* __restrict__ Bt, int ldb,
             void* __restrict__ Cv, int ldc,
             const float* __restrict__ bias,
             int K, int nreal, long long sstride)
{
  __shared__ __align__(16) u16 As[128 * 32];
  __shared__ __align__(16) u16 Bs[128 * 32];
  const int tid  = threadIdx.x;
  const int wave = tid >> 6, lane = tid & 63;
  const int m0 = blockIdx.x * 128, n0 = blockIdx.y * 128;
  const long long koff = (long long)blockIdx.z * K;
  A  += (size_t)m0 * lda + koff;
  Bt += (size_t)n0 * ldb + koff;

  // staging: tile is 128x32 bf16 = 8KB = 512 x 16B chunks; 256 threads x 2 chunks
  const int ch0 = tid, ch1 = tid + 256;
  const u16* ga0 = A  + (size_t)(ch0 >> 2) * lda + (ch0 & 3) * 8;
  const u16* ga1 = A  + (size_t)(ch1 >> 2) * lda + (ch1 & 3) * 8;
  const u16* gb0 = Bt + (size_t)(ch0 >> 2) * ldb + (ch0 & 3) * 8;
  const u16* gb1 = Bt + (size_t)(ch1 >> 2) * ldb + (ch1 & 3) * 8;
  u16* la0 = &As[ch0 * 8];   // = base + lane*16B per wave (gload_lds constraint)
  u16* la1 = &As[ch1 * 8];
  u16* lb0 = &Bs[ch0 * 8];
  u16* lb1 = &Bs[ch1 * 8];

  const int wr = (wave >> 1) * 64, wc = (wave & 1) * 64;  // wave's 64x64 quadrant
  const int fr = lane & 15, kq = lane >> 4;

  f32x4 acc[4][4] = {};

  for (int kt = 0; kt < K; kt += 32) {
    gl_lds16(ga0, la0); gl_lds16(ga1, la1);
    gl_lds16(gb0, lb0); gl_lds16(gb1, lb1);
    ga0 += 32; ga1 += 32; gb0 += 32; gb1 += 32;
    __syncthreads();                       // drains vmcnt (compiler-emitted)
    s16x8 af[4], bfv[4];
#pragma unroll
    for (int i = 0; i < 4; ++i)
      af[i] = *(const s16x8*)&As[(wr + i * 16 + fr) * 32 + kq * 8];
#pragma unroll
    for (int i = 0; i < 4; ++i)
      bfv[i] = *(const s16x8*)&Bs[(wc + i * 16 + fr) * 32 + kq * 8];
#pragma unroll
    for (int i = 0; i < 4; ++i)
#pragma unroll
      for (int j = 0; j < 4; ++j)
        acc[i][j] = __builtin_amdgcn_mfma_f32_16x16x32_bf16(af[i], bfv[j], acc[i][j], 0, 0, 0);
    __syncthreads();
  }

  // C/D frag mapping (m89-verified): col = lane&15, row = (lane>>4)*4 + r
#pragma unroll
  for (int j = 0; j < 4; ++j) {
    const int ccol = n0 + wc + j * 16 + fr;
    if (ccol >= nreal) continue;
    const float bv = BIAS ? bias[ccol] : 0.0f;
#pragma unroll
    for (int i = 0; i < 4; ++i) {
#pragma unroll
      for (int r = 0; r < 4; ++r) {
        const int crow = m0 + wr + i * 16 + kq * 4 + r;
        float v = acc[i][j][r] + bv;
        if (RELU) v = fmaxf(v, 0.0f);
        if (OBF) ((u16*)Cv)[(size_t)crow * ldc + ccol] = f2bf(v);
        else ((float*)Cv + (size_t)blockIdx.z * sstride)[(size_t)crow * ldc + ccol] = v;
      }
    }
  }
}

// ---------------------------------------------------------------------------
// transpose + f32->bf16:  W[K][N] f32  ->  Wt[Npad][K] bf16 (zero-padded rows)
// grid = (Npad/32, K/32), block = (32,8)
// ---------------------------------------------------------------------------
__global__ void tcvt(u16* __restrict__ Wt, const float* __restrict__ W,
                     int K, int N, int Npad)
{
  __shared__ float t[32][33];
  const int n0 = blockIdx.x * 32, k0 = blockIdx.y * 32;
  const int tx = threadIdx.x, ty = threadIdx.y;
#pragma unroll
  for (int i = 0; i < 4; ++i) {
    int k = k0 + ty + i * 8, n = n0 + tx;
    t[ty + i * 8][tx] = (k < K && n < N) ? W[(size_t)k * N + n] : 0.f;
  }
  __syncthreads();
#pragma unroll
  for (int i = 0; i < 4; ++i) {
    int n = n0 + ty + i * 8, k = k0 + tx;
    if (n < Npad) Wt[(size_t)n * K + k] = f2bf(t[tx][ty + i * 8]);
  }
}

// ---------------------------------------------------------------------------
// attention diagonal: diag[b,h,n] = softmax_m(q_n . k_m)[m=n]   (CAUSAL: m<=n)
// one block per (b,h); K-tile staged into LDS as f32; 192 threads (144 active)
// ---------------------------------------------------------------------------
template<bool CAUSAL>
__global__ __launch_bounds__(192)
void attn_diag(float* __restrict__ diag,
               const u16* __restrict__ Q, int ldq,
               const u16* __restrict__ Kp, int ldk)
{
  __shared__ float Kl[144][64];
  const int bh = blockIdx.x;             // b*8 + h
  const int b = bh >> 3, h = bh & 7;
  const int tid = threadIdx.x;

  for (int c = tid; c < 144 * 8; c += 192) {       // 8 x uint4 (8 bf16) per row
    int m = c >> 3, c8 = c & 7;
    uint4 u = *(const uint4*)(Kp + (size_t)(b * 144 + m) * ldk + h * 64 + c8 * 8);
    float* dst = &Kl[m][c8 * 8];
    dst[0] = __uint_as_float(u.x << 16); dst[1] = __uint_as_float(u.x & 0xffff0000u);
    dst[2] = __uint_as_float(u.y << 16); dst[3] = __uint_as_float(u.y & 0xffff0000u);
    dst[4] = __uint_as_float(u.z << 16); dst[5] = __uint_as_float(u.z & 0xffff0000u);
    dst[6] = __uint_as_float(u.w << 16); dst[7] = __uint_as_float(u.w & 0xffff0000u);
  }
  __syncthreads();
  if (tid >= 144) return;
  const int n = tid;
  float q[64];
  const uint4* qp = (const uint4*)(Q + (size_t)(b * 144 + n) * ldq + h * 64);
#pragma unroll
  for (int c = 0; c < 8; ++c) {
    uint4 u = qp[c];
    q[c*8+0] = __uint_as_float(u.x << 16); q[c*8+1] = __uint_as_float(u.x & 0xffff0000u);
    q[c*8+2] = __uint_as_float(u.y << 16); q[c*8+3] = __uint_as_float(u.y & 0xffff0000u);
    q[c*8+4] = __uint_as_float(u.z << 16); q[c*8+5] = __uint_as_float(u.z & 0xffff0000u);
    q[c*8+6] = __uint_as_float(u.w << 16); q[c*8+7] = __uint_as_float(u.w & 0xffff0000u);
  }
  const int mmax = CAUSAL ? n : 143;
  float mx = -3.4e38f, sm = 0.f, sdiag = 0.f;
  for (int m = 0; m <= mmax; ++m) {
    float s0 = 0, s1 = 0, s2 = 0, s3 = 0;
#pragma unroll
    for (int c = 0; c < 64; c += 4) {
      s0 = fmaf(q[c + 0], Kl[m][c + 0], s0);
      s1 = fmaf(q[c + 1], Kl[m][c + 1], s1);
      s2 = fmaf(q[c + 2], Kl[m][c + 2], s2);
      s3 = fmaf(q[c + 3], Kl[m][c + 3], s3);
    }
    float s = (s0 + s1) + (s2 + s3);
    if (m == n) sdiag = s;
    float nmx = fmaxf(mx, s);
    sm = sm * __expf(mx - nmx) + __expf(s - nmx);
    mx = nmx;
  }
  diag[(size_t)bh * 144 + n] = __expf(sdiag - mx) / sm;
}

// attn_out[r, d] = diag[b,h,n] * V[r, d]   (bf16 out)
__global__ void scale_v(u16* __restrict__ outb, const float* __restrict__ diag,
                        const u16* __restrict__ V, int ldv)
{
  const int idx = blockIdx.x * 256 + threadIdx.x;  // 4608*512
  const int r = idx >> 9, d = idx & 511;
  const int b = r / 144, n = r - b * 144;
  const int h = d >> 6;
  const float dg = diag[((size_t)b * 8 + h) * 144 + n];
  outb[(size_t)r * 512 + d] = f2bf(dg * bf2f(V[(size_t)r * ldv + d]));
}

// LayerNorm(A + B) * g + b  -> optional f32 out + optional bf16 out. 1 block/row.
__global__ __launch_bounds__(128)
void ln_dual(float* __restrict__ outf, u16* __restrict__ outb,
             const float* __restrict__ A, const float* __restrict__ Bv,
             const float* __restrict__ g, const float* __restrict__ be)
{
  const int r = blockIdx.x, t = threadIdx.x;      // 128 threads x 4 elems
  float4 a = ((const float4*)(A + (size_t)r * 512))[t];
  float4 b = ((const float4*)(Bv + (size_t)r * 512))[t];
  const float x0 = a.x + b.x, x1 = a.y + b.y, x2 = a.z + b.z, x3 = a.w + b.w;
  float s = x0 + x1 + x2 + x3;
  float q = x0 * x0 + x1 * x1 + x2 * x2 + x3 * x3;
#pragma unroll
  for (int off = 32; off > 0; off >>= 1) { s += __shfl_down(s, off); q += __shfl_down(q, off); }
  __shared__ float ss[2], qs[2];
  if ((t & 63) == 0) { ss[t >> 6] = s; qs[t >> 6] = q; }
  __syncthreads();
  s = ss[0] + ss[1]; q = qs[0] + qs[1];
  const float mean = s * (1.f / 512.f);
  const float var  = q * (1.f / 512.f) - mean * mean;
  const float rs = rsqrtf(var + 1e-5f);
  float4 gg = ((const float4*)g)[t];
  float4 bb = ((const float4*)be)[t];
  const float o0 = (x0 - mean) * rs * gg.x + bb.x;
  const float o1 = (x1 - mean) * rs * gg.y + bb.y;
  const float o2 = (x2 - mean) * rs * gg.z + bb.z;
  const float o3 = (x3 - mean) * rs * gg.w + bb.w;
  if (outf) ((float4*)(outf + (size_t)r * 512))[t] = make_float4(o0, o1, o2, o3);
  if (outb) {
    uint2 u;
    u.x = (u32)f2bf(o0) | ((u32)f2bf(o1) << 16);
    u.y = (u32)f2bf(o2) | ((u32)f2bf(o3) << 16);
    ((uint2*)(outb + (size_t)r * 512))[t] = u;
  }
}

__global__ void f32_to_bf16_vec(u16* __restrict__ o, const float* __restrict__ a)
{
  const int i = blockIdx.x * 256 + threadIdx.x;   // x4 floats
  float4 v = ((const float4*)a)[i];
  uint2 u;
  u.x = (u32)f2bf(v.x) | ((u32)f2bf(v.y) << 16);
  u.y = (u32)f2bf(v.z) | ((u32)f2bf(v.w) << 16);
  ((uint2*)o)[i] = u;
}

// ff[r, d] = b2[d] + sum_{s<8} parts[s][r][d]
__global__ void reduce_ff(float* __restrict__ ff, const float* __restrict__ parts,
                          const float* __restrict__ bias)
{
  const int i = blockIdx.x * 256 + threadIdx.x;   // x4 floats
  float4 acc = ((const float4*)bias)[i & 127];
#pragma unroll
  for (int s = 0; s < 8; ++s) {
    float4 p = ((const float4*)(parts + (size_t)s * 4608 * 512))[i];
    acc.x += p.x; acc.y += p.y; acc.z += p.z; acc.w += p.w;
  }
  ((float4*)ff)[i] = acc;
}

// xp[r, e] = x[r, e] for e<127 ; positional channel n/143 at e=127   (bf16)
__global__ void build_xp(u16* __restrict__ xp, const float* __restrict__ x)
{
  const int i = blockIdx.x * 256 + threadIdx.x;   // 4608*128
  const int r = i >> 7, e = i & 127;
  const float v = (e < 127) ? x[(size_t)r * 127 + e] : (float)(r % 144) * (1.f / 143.f);
  xp[i] = f2bf(v);
}

// ---------------------------------------------------------------------------
extern "C" void kernel_launch(void* const* d_in, const int* in_sizes, int n_in,
                              void* d_out, int out_size, void* d_ws, size_t ws_size,
                              hipStream_t stream)
{
  (void)in_sizes; (void)n_in; (void)out_size; (void)ws_size;
  const float* x    = (const float*)d_in[1];
  const float* Wenc = (const float*)d_in[3];
  const float* benc = (const float*)d_in[4];
  const float* Wq   = (const float*)d_in[5];
  const float* Wk   = (const float*)d_in[6];
  const float* Wv   = (const float*)d_in[7];
  const float* Wo   = (const float*)d_in[8];
  const float* bo   = (const float*)d_in[9];
  const float* ln1g = (const float*)d_in[10];
  const float* ln1b = (const float*)d_in[11];
  const float* ln2g = (const float*)d_in[12];
  const float* ln2b = (const float*)d_in[13];
  const float* ln3g = (const float*)d_in[14];
  const float* ln3b = (const float*)d_in[15];
  const float* W1   = (const float*)d_in[16];
  const float* b1   = (const float*)d_in[17];
  const float* W2   = (const float*)d_in[18];
  const float* b2   = (const float*)d_in[19];
  const float* Wdec = (const float*)d_in[20];
  const float* bdec = (const float*)d_in[21];

  char* w = (char*)d_ws;
  auto alloc = [&](size_t bytes) { void* p = (void*)w; w += (bytes + 255) & ~(size_t)255; return p; };
  u16*   wt_qkv = (u16*)alloc((size_t)1536 * 512 * 2);
  u16*   wt_o   = (u16*)alloc((size_t)512 * 512 * 2);
  u16*   wt_1   = (u16*)alloc((size_t)16384 * 512 * 2);
  u16*   wt_2   = (u16*)alloc((size_t)512 * 16384 * 2);
  u16*   wt_enc = (u16*)alloc((size_t)512 * 128 * 2);
  u16*   wt_dec = (u16*)alloc((size_t)128 * 512 * 2);
  float* xe_f   = (float*)alloc((size_t)4608 * 512 * 4);
  u16*   xe_bf  = (u16*)alloc((size_t)4608 * 512 * 2);
  u16*   out_bf = (u16*)alloc((size_t)4608 * 512 * 2);
  u16*   qkv_bf = (u16*)alloc((size_t)4608 * 1536 * 2);
  float* diag   = (float*)alloc((size_t)256 * 144 * 4);
  u16*   attn_bf= (u16*)alloc((size_t)4608 * 512 * 2);
  float* a1     = (float*)alloc((size_t)4608 * 512 * 4);
  u16*   qln_bf = (u16*)alloc((size_t)4608 * 512 * 2);
  float* a2     = (float*)alloc((size_t)4608 * 512 * 4);
  u16*   a2_bf  = (u16*)alloc((size_t)4608 * 512 * 2);
  u16*   hidden = (u16*)alloc((size_t)4608 * 8192 * 2);
  float* parts  = (float*)alloc((size_t)8 * 4608 * 512 * 4);
  float* ff     = (float*)alloc((size_t)4608 * 512 * 4);
  float* ao_f   = (float*)alloc((size_t)4608 * 512 * 4);
  u16*   ao_bf  = (u16*)alloc((size_t)4608 * 512 * 2);
  float* ff2    = a1;              // a1 is dead once qln_bf exists; reuse
  u16*   xp_bf  = hidden;          // encoder-only; hidden not live yet

  const long long PSTRIDE = (long long)4608 * 512;

  // ---- encoder ----
  tcvt<<<dim3(16, 4), dim3(32, 8), 0, stream>>>(wt_enc, Wenc, 128, 512, 512);
  tcvt<<<dim3(4, 16), dim3(32, 8), 0, stream>>>(wt_dec, Wdec, 512, 127, 128);
  build_xp<<<2304, 256, 0, stream>>>(xp_bf, x);
  gemm_bt<true, false, false><<<dim3(36, 4, 1), 256, 0, stream>>>(
      xp_bf, 128, wt_enc, 128, xe_f, 512, benc, 128, 512, 0);
  f32_to_bf16_vec<<<2304, 256, 0, stream>>>(xe_bf, xe_f);

  const u16* in_bf = xe_bf;
  for (int l = 0; l < 4; ++l) {
    const size_t wsz = (size_t)512 * 512;
    tcvt<<<dim3(16, 16), dim3(32, 8), 0, stream>>>(wt_qkv,               Wq + l * wsz, 512, 512, 512);
    tcvt<<<dim3(16, 16), dim3(32, 8), 0, stream>>>(wt_qkv + 512 * 512,   Wk + l * wsz, 512, 512, 512);
    tcvt<<<dim3(16, 16), dim3(32, 8), 0, stream>>>(wt_qkv + 1024 * 512,  Wv + l * wsz, 512, 512, 512);
    tcvt<<<dim3(16, 16), dim3(32, 8), 0, stream>>>(wt_o, Wo + l * wsz, 512, 512, 512);
    tcvt<<<dim3(512, 16), dim3(32, 8), 0, stream>>>(wt_1, W1 + (size_t)l * 512 * 16384, 512, 16384, 16384);
    tcvt<<<dim3(16, 512), dim3(32, 8), 0, stream>>>(wt_2, W2 + (size_t)l * 16384 * 512, 16384, 512, 512);

    // ---- MHA1 (causal; q,k,v from current layer input) ----
    gemm_bt<false, false, true><<<dim3(36, 12, 1), 256, 0, stream>>>(
        in_bf, 512, wt_qkv, 512, qkv_bf, 1536, nullptr, 512, 1536, 0);
    attn_diag<true><<<256, 192, 0, stream>>>(diag, qkv_bf, 1536, qkv_bf + 512, 1536);
    scale_v<<<9216, 256, 0, stream>>>(attn_bf, diag, qkv_bf + 1024, 1536);
    gemm_bt<true, false, false><<<dim3(36, 4, 1), 256, 0, stream>>>(
        attn_bf, 512, wt_o, 512, a1, 512, bo + l * 512, 512, 512, 0);
    ln_dual<<<4608, 128, 0, stream>>>(nullptr, qln_bf, a1, xe_f, ln1g + l * 512, ln1b + l * 512);

    // ---- MHA2 (no mask; q from LN1 out, k/v from xe) ----
    gemm_bt<false, false, true><<<dim3(36, 4, 1), 256, 0, stream>>>(
        qln_bf, 512, wt_qkv, 512, attn_bf, 512, nullptr, 512, 512, 0);        // q2
    gemm_bt<false, false, true><<<dim3(36, 8, 1), 256, 0, stream>>>(
        xe_bf, 512, wt_qkv + 512 * 512, 512, qkv_bf, 1024, nullptr, 512, 1024, 0); // k,v
    attn_diag<false><<<256, 192, 0, stream>>>(diag, attn_bf, 512, qkv_bf, 1024);
    scale_v<<<9216, 256, 0, stream>>>(attn_bf, diag, qkv_bf + 512, 1024);
    gemm_bt<true, false, false><<<dim3(36, 4, 1), 256, 0, stream>>>(
        attn_bf, 512, wt_o, 512, a2, 512, bo + l * 512, 512, 512, 0);
    f32_to_bf16_vec<<<2304, 256, 0, stream>>>(a2_bf, a2);

    // ---- FFN1: ff = relu(a2 @ W1 + b1) @ W2 + b2 (2 chunks x split-K=4) ----
    for (int c = 0; c < 2; ++c) {
      gemm_bt<true, true, true><<<dim3(36, 64, 1), 256, 0, stream>>>(
          a2_bf, 512, wt_1 + (size_t)c * 8192 * 512, 512, hidden, 8192,
          b1 + l * 16384 + c * 8192, 512, 8192, 0);
      gemm_bt<false, false, false><<<dim3(36, 4, 4), 256, 0, stream>>>(
          hidden, 8192, wt_2 + c * 8192, 16384,
          parts + (size_t)c * 4 * 4608 * 512, 512, nullptr, 2048, 512, PSTRIDE);
    }
    reduce_ff<<<2304, 256, 0, stream>>>(ff, parts, b2 + l * 512);
    ln_dual<<<4608, 128, 0, stream>>>(ao_f, ao_bf, ff, a2, ln2g + l * 512, ln2b + l * 512);

    // ---- FFN2 on ao ----
    for (int c = 0; c < 2; ++c) {
      gemm_bt<true, true, true><<<dim3(36, 64, 1), 256, 0, stream>>>(
          ao_bf, 512, wt_1 + (size_t)c * 8192 * 512, 512, hidden, 8192,
          b1 + l * 16384 + c * 8192, 512, 8192, 0);
      gemm_bt<false, false, false><<<dim3(36, 4, 4), 256, 0, stream>>>(
          hidden, 8192, wt_2 + c * 8192, 16384,
          parts + (size_t)c * 4 * 4608 * 512, 512, nullptr, 2048, 512, PSTRIDE);
    }
    reduce_ff<<<2304, 256, 0, stream>>>(ff2, parts, b2 + l * 512);
    ln_dual<<<4608, 128, 0, stream>>>(nullptr, out_bf, ao_f, ff2, ln3g + l * 512, ln3b + l * 512);
    in_bf = out_bf;
  }

  // ---- decoder: d_out = out @ Wdec + bdec  (N=127, padded Bt to 128) ----
  gemm_bt<true, false, false><<<dim3(36, 1, 1), 256, 0, stream>>>(
      in_bf, 512, wt_dec, 512, (float*)d_out, 127, bdec, 512, 127, 0);
}